// Round 6
// baseline (287.463 us; speedup 1.0000x reference)
//
#include <hip/hip_runtime.h>

#define CHN 96
#define IMG_H 256
#define IMG_W 256
#define STRIP 64          // rows per wave
#define WPB 8             // waves per block
#define GRP 8             // rows per pipelined group

typedef float vfloat4 __attribute__((ext_vector_type(4)));

struct Row { float l, x, y, z, w, r; };

__device__ __forceinline__ Row mkrow(vfloat4 v, int lane) {
    Row r;
    r.x = v.x; r.y = v.y; r.z = v.z; r.w = v.w;
    r.l = __shfl_up(v.w, 1);
    r.r = __shfl_down(v.x, 1);
    if (lane == 0)  r.l = 0.f;   // x = -1 zero pad
    if (lane == 63) r.r = 0.f;   // x = 256 zero pad
    return r;
}

__device__ __forceinline__ vfloat4 ldrow(const float* xp, int yy, int col) {
    if (yy < IMG_H)
        return __builtin_nontemporal_load(
            (const vfloat4*)(xp + (size_t)yy * IMG_W + col));
    return (vfloat4){0.f, 0.f, 0.f, 0.f};
}

__device__ __forceinline__ vfloat4 stencil(const Row& a, const Row& b, const Row& c,
                                           float w0, float w1, float w2,
                                           float w3, float w4, float w5,
                                           float w6, float w7, float w8) {
    vfloat4 o;
    o.x = w0*a.l + w1*a.x + w2*a.y
        + w3*b.l + w4*b.x + w5*b.y
        + w6*c.l + w7*c.x + w8*c.y;
    o.y = w0*a.x + w1*a.y + w2*a.z
        + w3*b.x + w4*b.y + w5*b.z
        + w6*c.x + w7*c.y + w8*c.z;
    o.z = w0*a.y + w1*a.z + w2*a.w
        + w3*b.y + w4*b.z + w5*b.w
        + w6*c.y + w7*c.z + w8*c.w;
    o.w = w0*a.z + w1*a.w + w2*a.r
        + w3*b.z + w4*b.w + w5*b.r
        + w6*c.z + w7*c.w + w8*c.r;
    return o;
}

// DIAGNOSTIC build: runs the identical strip walk TWICE per dispatch so the
// kernel exceeds the ~235us poison fills and lands in rocprof's top-5 with
// its own FETCH_SIZE / WRITE_SIZE / VGPR / Occupancy counters. Output is
// written identically by both passes -> still correct & deterministic.
__global__ __launch_bounds__(WPB * 64)
void sharpen3x3_diag(const float* __restrict__ x,
                     const float* __restrict__ kern,
                     float* __restrict__ out)
{
    const int lane = threadIdx.x & 63;
    const int wave = threadIdx.x >> 6;

    const int strip_id = blockIdx.x * WPB + wave;            // 0..6143
    const int spp      = IMG_H / STRIP;                      // 4 strips per plane
    const int plane    = strip_id / spp;                     // n*CHN + c
    const int sy       = (strip_id % spp) * STRIP;           // first output row
    const int c        = plane % CHN;

    const float* kw = kern + ((size_t)c * CHN + c) * 9;
    const float w0 = kw[0], w1 = kw[1], w2 = kw[2];
    const float w3 = kw[3], w4 = kw[4], w5 = kw[5];
    const float w6 = kw[6], w7 = kw[7], w8 = kw[8];

    const float* xp = x   + (size_t)plane * IMG_H * IMG_W;
    float*       op = out + (size_t)plane * IMG_H * IMG_W;
    const int col = 4 * lane;

    #pragma unroll 1
    for (int rep = 0; rep < 2; ++rep) {
        Row prev, cur;
        if (sy == 0) {
            prev = Row{0.f, 0.f, 0.f, 0.f, 0.f, 0.f};
        } else {
            prev = mkrow(ldrow(xp, sy - 1, col), lane);
        }
        cur = mkrow(ldrow(xp, sy, col), lane);

        vfloat4 va[GRP];
        #pragma unroll
        for (int j = 0; j < GRP; ++j) va[j] = ldrow(xp, sy + 1 + j, col);

        #pragma unroll 1
        for (int g = 0; g < STRIP / GRP; ++g) {
            const int y = sy + g * GRP;

            vfloat4 vb[GRP];
            if (g + 1 < STRIP / GRP) {
                #pragma unroll
                for (int j = 0; j < GRP; ++j)
                    vb[j] = ldrow(xp, y + GRP + 1 + j, col);
            } else {
                #pragma unroll
                for (int j = 0; j < GRP; ++j)
                    vb[j] = (vfloat4){0.f, 0.f, 0.f, 0.f};
            }

            #pragma unroll
            for (int j = 0; j < GRP; ++j) {
                Row n = mkrow(va[j], lane);
                vfloat4 o = stencil(prev, cur, n,
                                    w0,w1,w2,w3,w4,w5,w6,w7,w8);
                __builtin_nontemporal_store(
                    o, (vfloat4*)(op + (size_t)(y + j) * IMG_W + col));
                prev = cur;
                cur  = n;
            }

            #pragma unroll
            for (int j = 0; j < GRP; ++j) va[j] = vb[j];
        }
    }
}

extern "C" void kernel_launch(void* const* d_in, const int* in_sizes, int n_in,
                              void* d_out, int out_size, void* d_ws, size_t ws_size,
                              hipStream_t stream) {
    const float* x    = (const float*)d_in[0];
    const float* kern = (const float*)d_in[1];
    float* out        = (float*)d_out;

    const int n_strips = 16 * CHN * (IMG_H / STRIP);   // 6144 waves
    const int grid     = n_strips / WPB;               // 768 blocks

    hipLaunchKernelGGL(sharpen3x3_diag, dim3(grid), dim3(WPB * 64),
                       0, stream, x, kern, out);
}

// Round 7
// 270.352 us; speedup vs baseline: 1.0633x; 1.0633x over previous
//
#include <hip/hip_runtime.h>

#define CHN 96
#define IMG_H 256
#define IMG_W 256
#define STRIP 16          // rows per wave: 24576 waves total (4x TLP vs R3)
#define WPB 4             // waves per block (256 threads) - fine dispatch grain
#define GRP 4             // rows per prefetch group
#define NG (STRIP / GRP)  // 4 groups, fully unrolled

typedef float vfloat4 __attribute__((ext_vector_type(4)));

__device__ __forceinline__ vfloat4 ldrow(const float* xp, int yy, int col) {
    // yy >= 0 guaranteed by callers; zero-fill past the bottom edge.
    // Cached loads: halo rows shared across strips + L3 retention across replays.
    if (yy < IMG_H)
        return *(const vfloat4*)(xp + (size_t)yy * IMG_W + col);
    return (vfloat4){0.f, 0.f, 0.f, 0.f};
}

// Horizontal 3-tap sum for the lane's 4 pixels (zero pad at x=-1 / x=256).
__device__ __forceinline__ vfloat4 hsum3(vfloat4 v, int lane) {
    float l = __shfl_up(v.w, 1);
    float r = __shfl_down(v.x, 1);
    if (lane == 0)  l = 0.f;
    if (lane == 63) r = 0.f;
    float t1 = v.x + v.y;
    float t2 = v.z + v.w;
    vfloat4 h;
    h.x = l   + t1;
    h.y = t1  + v.z;
    h.z = v.y + t2;
    h.w = t2  + r;
    return h;
}

// 8 wave-slots/SIMD requested -> VGPR capped at 64 -> 32 waves/CU eligible.
__global__ __launch_bounds__(WPB * 64, 8)
void sharpen3x3_tlp(const float* __restrict__ x,
                    const float* __restrict__ kern,
                    float* __restrict__ out)
{
    const int lane = threadIdx.x & 63;
    const int wave = threadIdx.x >> 6;

    const int strip_id = blockIdx.x * WPB + wave;            // 0..24575
    const int spp      = IMG_H / STRIP;                      // 16 strips per plane
    const int plane    = strip_id / spp;                     // n*CHN + c
    const int sy       = (strip_id % spp) * STRIP;           // first output row
    const int c        = plane % CHN;

    // Diagonal 3x3 block of the dense (C,C,3,3) kernel; sharpen has one
    // neighbor weight kw[0] and one center weight kw[4]:
    //   out = wn * box3x3_sum + (w_center - wn) * center
    const float* kw = kern + ((size_t)c * CHN + c) * 9;
    const float wn = kw[0];
    const float wd = kw[4] - wn;

    const float* xp = x   + (size_t)plane * IMG_H * IMG_W;
    float*       op = out + (size_t)plane * IMG_H * IMG_W;
    const int col = 4 * lane;

    // prime: group 0 input rows sy+1 .. sy+GRP
    vfloat4 buf[2][GRP];
    #pragma unroll
    for (int j = 0; j < GRP; ++j) buf[0][j] = ldrow(xp, sy + 1 + j, col);

    vfloat4 hprev, hcur, ccur;
    if (sy == 0) {
        hprev = (vfloat4){0.f, 0.f, 0.f, 0.f};
    } else {
        hprev = hsum3(*(const vfloat4*)(xp + (size_t)(sy - 1) * IMG_W + col), lane);
    }
    {
        vfloat4 v0 = *(const vfloat4*)(xp + (size_t)sy * IMG_W + col);
        hcur = hsum3(v0, lane);
        ccur = v0;
    }

    #pragma unroll
    for (int g = 0; g < NG; ++g) {
        // prefetch next group while computing current (static indices only)
        if (g + 1 < NG) {
            #pragma unroll
            for (int j = 0; j < GRP; ++j)
                buf[(g + 1) & 1][j] = ldrow(xp, sy + (g + 1) * GRP + 1 + j, col);
        }
        #pragma unroll
        for (int j = 0; j < GRP; ++j) {
            const int y = sy + g * GRP + j;
            vfloat4 hn = hsum3(buf[g & 1][j], lane);   // input row y+1
            vfloat4 s  = hprev + hcur + hn;            // 3x3 box sum
            vfloat4 o  = s * wn + ccur * wd;
            __builtin_nontemporal_store(
                o, (vfloat4*)(op + (size_t)y * IMG_W + col));
            hprev = hcur;
            hcur  = hn;
            ccur  = buf[g & 1][j];
        }
    }
}

extern "C" void kernel_launch(void* const* d_in, const int* in_sizes, int n_in,
                              void* d_out, int out_size, void* d_ws, size_t ws_size,
                              hipStream_t stream) {
    const float* x    = (const float*)d_in[0];
    const float* kern = (const float*)d_in[1];
    float* out        = (float*)d_out;

    const int n_strips = 16 * CHN * (IMG_H / STRIP);   // 24576 waves
    const int grid     = n_strips / WPB;               // 6144 blocks

    hipLaunchKernelGGL(sharpen3x3_tlp, dim3(grid), dim3(WPB * 64),
                       0, stream, x, kern, out);
}

// Round 8
// 140.389 us; speedup vs baseline: 2.0476x; 1.9257x over previous
//
#include <hip/hip_runtime.h>

#define CHN 96
#define IMG_H 256
#define IMG_W 256
#define STRIP 32          // rows per wave: 12288 waves, fine-grained
#define WPB 4             // waves per block (256 threads)
#define GRP 8             // rows per pipelined group (R3's winning depth)
#define NG (STRIP / GRP)  // 4 groups per strip

typedef float vfloat4 __attribute__((ext_vector_type(4)));

__device__ __forceinline__ vfloat4 ldrow(const float* xp, int yy, int col) {
    // yy >= 0 guaranteed by callers; zero-fill past the bottom edge.
    if (yy < IMG_H)
        return __builtin_nontemporal_load(
            (const vfloat4*)(xp + (size_t)yy * IMG_W + col));
    return (vfloat4){0.f, 0.f, 0.f, 0.f};
}

// Horizontal 3-tap sum for the lane's 4 pixels (zero pad at x=-1 / x=256).
__device__ __forceinline__ vfloat4 hsum3(vfloat4 v, int lane) {
    float l = __shfl_up(v.w, 1);
    float r = __shfl_down(v.x, 1);
    if (lane == 0)  l = 0.f;
    if (lane == 63) r = 0.f;
    float t1 = v.x + v.y;
    float t2 = v.z + v.w;
    vfloat4 h;
    h.x = l   + t1;
    h.y = t1  + v.z;
    h.z = v.y + t2;
    h.w = t2  + r;
    return h;
}

// NOTE: no min-waves clause -- R7 showed forcing occupancy below the natural
// register need (~85 VGPR here) makes the allocator spill to scratch (VGPR=32,
// 1.5 TB/s). Fine-grained blocks provide the machine fill instead.
__global__ __launch_bounds__(WPB * 64)
void sharpen3x3_fine(const float* __restrict__ x,
                     const float* __restrict__ kern,
                     float* __restrict__ out)
{
    const int lane = threadIdx.x & 63;
    const int wave = threadIdx.x >> 6;

    const int strip_id = blockIdx.x * WPB + wave;            // 0..12287
    const int spp      = IMG_H / STRIP;                      // 8 strips per plane
    const int plane    = strip_id / spp;                     // n*CHN + c
    const int sy       = (strip_id % spp) * STRIP;           // first output row
    const int c        = plane % CHN;

    // Diagonal 3x3 block of the dense (C,C,3,3) kernel; sharpen has one
    // neighbor weight kw[0] and one center weight kw[4]:
    //   out = wn * box3x3_sum + (w_center - wn) * center
    const float* kw = kern + ((size_t)c * CHN + c) * 9;
    const float wn = kw[0];
    const float wd = kw[4] - wn;

    const float* xp = x   + (size_t)plane * IMG_H * IMG_W;
    float*       op = out + (size_t)plane * IMG_H * IMG_W;
    const int col = 4 * lane;

    // prime: group 0 input rows sy+1 .. sy+GRP
    vfloat4 va[GRP];
    #pragma unroll
    for (int j = 0; j < GRP; ++j) va[j] = ldrow(xp, sy + 1 + j, col);

    vfloat4 hprev, hcur, ccur;
    if (sy == 0) {
        hprev = (vfloat4){0.f, 0.f, 0.f, 0.f};
    } else {
        hprev = hsum3(*(const vfloat4*)(xp + (size_t)(sy - 1) * IMG_W + col), lane);
    }
    {
        vfloat4 v0 = *(const vfloat4*)(xp + (size_t)sy * IMG_W + col);
        hcur = hsum3(v0, lane);
        ccur = v0;
    }

    #pragma unroll 1
    for (int g = 0; g < NG; ++g) {
        const int y = sy + g * GRP;

        // prefetch next group while computing current (R3 drain-copy pattern)
        vfloat4 vb[GRP];
        if (g + 1 < NG) {
            #pragma unroll
            for (int j = 0; j < GRP; ++j)
                vb[j] = ldrow(xp, y + GRP + 1 + j, col);
        } else {
            #pragma unroll
            for (int j = 0; j < GRP; ++j)
                vb[j] = (vfloat4){0.f, 0.f, 0.f, 0.f};
        }

        #pragma unroll
        for (int j = 0; j < GRP; ++j) {
            vfloat4 hn = hsum3(va[j], lane);     // input row y+j+1
            vfloat4 s  = hprev + hcur + hn;      // 3x3 box sum
            vfloat4 o  = s * wn + ccur * wd;
            __builtin_nontemporal_store(
                o, (vfloat4*)(op + (size_t)(y + j) * IMG_W + col));
            hprev = hcur;
            hcur  = hn;
            ccur  = va[j];
        }

        #pragma unroll
        for (int j = 0; j < GRP; ++j) va[j] = vb[j];
    }
}

extern "C" void kernel_launch(void* const* d_in, const int* in_sizes, int n_in,
                              void* d_out, int out_size, void* d_ws, size_t ws_size,
                              hipStream_t stream) {
    const float* x    = (const float*)d_in[0];
    const float* kern = (const float*)d_in[1];
    float* out        = (float*)d_out;

    const int n_strips = 16 * CHN * (IMG_H / STRIP);   // 12288 waves
    const int grid     = n_strips / WPB;               // 3072 blocks

    hipLaunchKernelGGL(sharpen3x3_fine, dim3(grid), dim3(WPB * 64),
                       0, stream, x, kern, out);
}